// Round 5
// baseline (222.713 us; speedup 1.0000x reference)
//
#include <hip/hip_runtime.h>
#include <hip/hip_bf16.h>

#define BB 4
#define LL 2048
#define DM 1024
#define NH 16
#define FEAT 16
#define HD 64
#define CHUNK 128
#define NCHUNK 16
#define NEXT 80               // 64 v-cols + 1 ones-col + 15 pad
#define SROW 23040            // 18 dtiles x 80 e x 16 d = per-(bh,c) slab elems
#define EPS 1e-12f
#define INV_R2RD 0.17677669529663688f   // 1/(4*sqrt(2))
#define QKVLD 1536

typedef short bf16x8_t __attribute__((ext_vector_type(8)));
typedef float f32x4_t  __attribute__((ext_vector_type(4)));

__device__ __forceinline__ float b2f(unsigned short u) {
    union { unsigned int i; float f; } x; x.i = ((unsigned int)u) << 16; return x.f;
}
__device__ __forceinline__ unsigned short f2b(float f) {
    __hip_bfloat16 h = __float2bfloat16(f);
    return *reinterpret_cast<unsigned short*>(&h);
}

// ---------------------------------------------------------------------------
// Weight casts only (hs cast is fused into the qkv GEMM's A staging).
// ---------------------------------------------------------------------------
__global__ __launch_bounds__(256)
void cast_w(const float* __restrict__ wq, const float* __restrict__ wk,
            const float* __restrict__ wv, const float* __restrict__ wo,
            unsigned short* __restrict__ wqkv, unsigned short* __restrict__ wo_bf)
{
    const int i = (blockIdx.x * 256 + threadIdx.x) * 4;
    const float* s; unsigned short* d;
    if (i < 262144)       { s = wq + i;             d = wqkv + i; }
    else if (i < 524288)  { s = wk + (i - 262144);  d = wqkv + i; }
    else if (i < 1572864) { s = wv + (i - 524288);  d = wqkv + i; }
    else if (i < 2621440) { s = wo + (i - 1572864); d = wo_bf + (i - 1572864); }
    else return;
    float4 v = *(const float4*)s;
    ushort4 o; o.x = f2b(v.x); o.y = f2b(v.y); o.z = f2b(v.z); o.w = f2b(v.w);
    *(ushort4*)d = o;
}

// ---------------------------------------------------------------------------
// bf16 MFMA GEMM: C[M,N] = A[M,K] @ Bw[N,K]^T (fp32 acc).
// 128x128 tile, BK=32, 256 threads, m97 recipe + XOR bank swizzle:
// LDS physical chunk pc holds global chunk pc ^ ((row>>1)&3)  -> fragment
// ds_read_b128s land 2-way (free) instead of 8-way.
// ---------------------------------------------------------------------------
template <typename OutT>
__global__ __launch_bounds__(256)
void gemm_bf16(const unsigned short* __restrict__ A, const unsigned short* __restrict__ Bw,
               OutT* __restrict__ C, int M, int N, int K, int lda, int ldb, int ldc)
{
    __shared__ unsigned short As[128 * 32];
    __shared__ unsigned short Bs[128 * 32];
    const int tid  = threadIdx.x;
    const int wave = tid >> 6, lane = tid & 63;
    const int m0 = blockIdx.y * 128, n0 = blockIdx.x * 128;
    const int wm = (wave >> 1) * 64, wn = (wave & 1) * 64;
    const int srow = tid >> 2;
    const int skc  = tid & 3;
    const int gkc  = skc ^ ((srow >> 1) & 3);   // swizzled global chunk
    const int ml = lane & 15, qq = lane >> 4;

    f32x4_t acc[4][4];
#pragma unroll
    for (int i = 0; i < 4; ++i)
#pragma unroll
        for (int j = 0; j < 4; ++j) acc[i][j] = (f32x4_t){0.f, 0.f, 0.f, 0.f};

    for (int k0 = 0; k0 < K; k0 += 32) {
#pragma unroll
        for (int p = 0; p < 2; ++p) {
            const int row = p * 64 + srow;
            const unsigned short* ga = A  + (size_t)(m0 + row) * lda + k0 + gkc * 8;
            const unsigned short* gb = Bw + (size_t)(n0 + row) * ldb + k0 + gkc * 8;
            unsigned short* la = As + (size_t)(p * 64 + wave * 16) * 32;
            unsigned short* lb = Bs + (size_t)(p * 64 + wave * 16) * 32;
            __builtin_amdgcn_global_load_lds((const __attribute__((address_space(1))) void*)ga,
                                             (__attribute__((address_space(3))) void*)la, 16, 0, 0);
            __builtin_amdgcn_global_load_lds((const __attribute__((address_space(1))) void*)gb,
                                             (__attribute__((address_space(3))) void*)lb, 16, 0, 0);
        }
        __syncthreads();
        bf16x8_t af[4], bfr[4];
#pragma unroll
        for (int i = 0; i < 4; ++i) {
            const int ra = wm + i * 16 + ml, rb = wn + i * 16 + ml;
            af[i]  = *(const bf16x8_t*)(As + ra * 32 + (qq ^ ((ra >> 1) & 3)) * 8);
            bfr[i] = *(const bf16x8_t*)(Bs + rb * 32 + (qq ^ ((rb >> 1) & 3)) * 8);
        }
#pragma unroll
        for (int i = 0; i < 4; ++i)
#pragma unroll
            for (int j = 0; j < 4; ++j)
                acc[i][j] = __builtin_amdgcn_mfma_f32_16x16x32_bf16(af[i], bfr[j], acc[i][j], 0, 0, 0);
        __syncthreads();
    }
#pragma unroll
    for (int i = 0; i < 4; ++i) {
        const int rbase = m0 + wm + i * 16 + qq * 4;
#pragma unroll
        for (int j = 0; j < 4; ++j) {
            const int col = n0 + wn + j * 16 + ml;
#pragma unroll
            for (int r = 0; r < 4; ++r) {
                const float v = acc[i][j][r];
                if constexpr (sizeof(OutT) == 2) {
                    ((unsigned short*)C)[(size_t)(rbase + r) * ldc + col] = f2b(v);
                } else {
                    ((float*)C)[(size_t)(rbase + r) * ldc + col] = v;
                }
            }
        }
    }
}

// ---------------------------------------------------------------------------
// qkv GEMM with FUSED fp32->bf16 cast on the A operand (hs read as fp32,
// converted during staging, ds_write_b128 into the swizzled LDS layout).
// B (pre-cast weights) keeps global_load_lds. Same tile/swizzle as above.
// ---------------------------------------------------------------------------
__global__ __launch_bounds__(256)
void gemm_qkv(const float* __restrict__ A, const unsigned short* __restrict__ Bw,
              unsigned short* __restrict__ C, int M, int N, int K, int lda, int ldb, int ldc)
{
    __shared__ unsigned short As[128 * 32];
    __shared__ unsigned short Bs[128 * 32];
    const int tid  = threadIdx.x;
    const int wave = tid >> 6, lane = tid & 63;
    const int m0 = blockIdx.y * 128, n0 = blockIdx.x * 128;
    const int wm = (wave >> 1) * 64, wn = (wave & 1) * 64;
    const int srow = tid >> 2;
    const int skc  = tid & 3;
    const int gkc  = skc ^ ((srow >> 1) & 3);
    const int ml = lane & 15, qq = lane >> 4;

    f32x4_t acc[4][4];
#pragma unroll
    for (int i = 0; i < 4; ++i)
#pragma unroll
        for (int j = 0; j < 4; ++j) acc[i][j] = (f32x4_t){0.f, 0.f, 0.f, 0.f};

    for (int k0 = 0; k0 < K; k0 += 32) {
#pragma unroll
        for (int p = 0; p < 2; ++p) {
            const int row = p * 64 + srow;
            // A: fp32 load + cvt + manual LDS write (swizzled content)
            const float* gaf = A + (size_t)(m0 + row) * lda + k0 + gkc * 8;
            float4 a0 = *(const float4*)gaf;
            float4 a1 = *(const float4*)(gaf + 4);
            unsigned short pk[8];
            pk[0] = f2b(a0.x); pk[1] = f2b(a0.y); pk[2] = f2b(a0.z); pk[3] = f2b(a0.w);
            pk[4] = f2b(a1.x); pk[5] = f2b(a1.y); pk[6] = f2b(a1.z); pk[7] = f2b(a1.w);
            *(bf16x8_t*)(As + (size_t)(p * 64 + srow) * 32 + skc * 8) = *(const bf16x8_t*)pk;
            // B: async global->LDS
            const unsigned short* gb = Bw + (size_t)(n0 + row) * ldb + k0 + gkc * 8;
            unsigned short* lb = Bs + (size_t)(p * 64 + wave * 16) * 32;
            __builtin_amdgcn_global_load_lds((const __attribute__((address_space(1))) void*)gb,
                                             (__attribute__((address_space(3))) void*)lb, 16, 0, 0);
        }
        __syncthreads();
        bf16x8_t af[4], bfr[4];
#pragma unroll
        for (int i = 0; i < 4; ++i) {
            const int ra = wm + i * 16 + ml, rb = wn + i * 16 + ml;
            af[i]  = *(const bf16x8_t*)(As + ra * 32 + (qq ^ ((ra >> 1) & 3)) * 8);
            bfr[i] = *(const bf16x8_t*)(Bs + rb * 32 + (qq ^ ((rb >> 1) & 3)) * 8);
        }
#pragma unroll
        for (int i = 0; i < 4; ++i)
#pragma unroll
            for (int j = 0; j < 4; ++j)
                acc[i][j] = __builtin_amdgcn_mfma_f32_16x16x32_bf16(af[i], bfr[j], acc[i][j], 0, 0, 0);
        __syncthreads();
    }
#pragma unroll
    for (int i = 0; i < 4; ++i) {
        const int rbase = m0 + wm + i * 16 + qq * 4;
#pragma unroll
        for (int j = 0; j < 4; ++j) {
            const int col = n0 + wn + j * 16 + ml;
#pragma unroll
            for (int r = 0; r < 4; ++r)
                C[(size_t)(rbase + r) * ldc + col] = f2b(acc[i][j][r]);
        }
    }
}

// ---------------------------------------------------------------------------
// state_kernel: per (bh,c) computes S_c = Kf^T @ V_ext (MFMA), stored in the
// TILED layout: slab[dtile 0..17][e 0..79][dlocal 0..15], d = dtile*16+dlocal.
// Feature order d: [1][q/2 x16][0 x7][qxq/(4sqrt2) x256][0 x8]; e=64 -> z.
// ---------------------------------------------------------------------------
__global__ __launch_bounds__(256)
void state_kernel(const unsigned short* __restrict__ qkv, unsigned short* __restrict__ STg)
{
    __shared__ unsigned short KT[16 * 136];   // K transposed [f][j], padded
    __shared__ unsigned short VT[80 * 136];   // V_ext transposed [e][j], padded

    const int x = blockIdx.x;
    const int c = x & 15, bh = x >> 4;
    const int b = bh >> 4, h = bh & 15;
    const int tid = threadIdx.x;
    const int wave = tid >> 6, lane = tid & 63;
    const int ml = lane & 15, kg8 = (lane >> 4) * 8;
    const size_t rowbase = (size_t)(b * LL + c * CHUNK);
    const size_t Sbase = (size_t)x * SROW;

    {
        const int row = tid >> 1, half = tid & 1;
        uint4 kv = *(const uint4*)(qkv + (rowbase + row) * QKVLD + 256 + h * 16 + half * 8);
        const unsigned short* kp = (const unsigned short*)&kv;
#pragma unroll
        for (int i = 0; i < 8; ++i) KT[(half * 8 + i) * 136 + row] = kp[i];
#pragma unroll
        for (int cc = 0; cc < 4; ++cc) {
            uint4 vv = *(const uint4*)(qkv + (rowbase + row) * QKVLD + 512 + h * 64 + half * 32 + cc * 8);
            const unsigned short* vp = (const unsigned short*)&vv;
#pragma unroll
            for (int i = 0; i < 8; ++i) VT[(half * 32 + cc * 8 + i) * 136 + row] = vp[i];
        }
        if (half == 0) {
            VT[64 * 136 + row] = 0x3F80;   // ones column
        } else {
#pragma unroll
            for (int e = 65; e < 80; ++e) VT[e * 136 + row] = 0;
        }
    }
    __syncthreads();

    bf16x8_t bfr[5][4];
#pragma unroll
    for (int nt = 0; nt < 5; ++nt)
#pragma unroll
        for (int ks = 0; ks < 4; ++ks)
            bfr[nt][ks] = *(const bf16x8_t*)&VT[(nt * 16 + ml) * 136 + ks * 32 + kg8];

    for (int mt = wave; mt < 18; mt += 4) {
        const int d = mt * 16 + ml;
        bf16x8_t af[4];
#pragma unroll
        for (int ks = 0; ks < 4; ++ks) {
            const int jb = ks * 32 + kg8;
            unsigned short o[8];
            if (d >= 24 && d < 280) {
                const int e = d - 24, a = e >> 4, bq = e & 15;
                bf16x8_t ka = *(const bf16x8_t*)&KT[a  * 136 + jb];
                bf16x8_t kb = *(const bf16x8_t*)&KT[bq * 136 + jb];
#pragma unroll
                for (int j = 0; j < 8; ++j)
                    o[j] = f2b(b2f((unsigned short)ka[j]) * b2f((unsigned short)kb[j]) * INV_R2RD);
            } else if (d == 0) {
#pragma unroll
                for (int j = 0; j < 8; ++j) o[j] = 0x3F80;
            } else if (d <= 16) {
                bf16x8_t kx = *(const bf16x8_t*)&KT[(d - 1) * 136 + jb];
#pragma unroll
                for (int j = 0; j < 8; ++j) o[j] = f2b(b2f((unsigned short)kx[j]) * 0.5f);
            } else {
#pragma unroll
                for (int j = 0; j < 8; ++j) o[j] = 0;
            }
            af[ks] = *(const bf16x8_t*)o;
        }
        f32x4_t acc[5];
#pragma unroll
        for (int nt = 0; nt < 5; ++nt) acc[nt] = (f32x4_t){0.f, 0.f, 0.f, 0.f};
#pragma unroll
        for (int nt = 0; nt < 5; ++nt)
#pragma unroll
            for (int ks = 0; ks < 4; ++ks)
                acc[nt] = __builtin_amdgcn_mfma_f32_16x16x32_bf16(af[ks], bfr[nt][ks], acc[nt], 0, 0, 0);
#pragma unroll
        for (int nt = 0; nt < 5; ++nt) {
            ushort4 pk;
            pk.x = f2b(acc[nt][0]); pk.y = f2b(acc[nt][1]);
            pk.z = f2b(acc[nt][2]); pk.w = f2b(acc[nt][3]);
            *(ushort4*)(STg + Sbase + (size_t)mt * 1280 + (nt * 16 + ml) * 16 + (lane >> 4) * 4) = pk;
        }
    }
}

// ---------------------------------------------------------------------------
// scan: exclusive prefix over the 16 chunks, elementwise, uint4 per thread.
// ---------------------------------------------------------------------------
__global__ __launch_bounds__(256)
void scan_S(unsigned short* __restrict__ STg) {
    const int bh  = blockIdx.y;
    const int idx = blockIdx.x * 256 + threadIdx.x;   // uint4 index, 0..2879
    if (idx >= SROW / 8) return;
    const size_t base = (size_t)bh * NCHUNK * SROW + (size_t)idx * 8;
    float acc[8] = {};
    for (int c = 0; c < NCHUNK; ++c) {
        unsigned short* p = STg + base + (size_t)c * SROW;
        uint4 v = *(const uint4*)p;
        const unsigned short* vp = (const unsigned short*)&v;
        uint4 o;
        unsigned short* op = (unsigned short*)&o;
#pragma unroll
        for (int i = 0; i < 8; ++i) { op[i] = f2b(acc[i]); acc[i] += b2f(vp[i]); }
        *(uint4*)p = o;
    }
}

// ---------------------------------------------------------------------------
// out_kernel: per (bh,c), 256 threads / 4 waves (unchanged from round 4).
// ---------------------------------------------------------------------------
#define OFF_VT 0
#define OFF_QP 0
#define OFF_KP 5120
#define OFF_A  10880
#define OFF_QS 28288

__global__ __launch_bounds__(256)
void out_kernel(const unsigned short* __restrict__ qkv_ro, const unsigned short* __restrict__ STg,
                unsigned short* __restrict__ qkv_w)
{
    __shared__ unsigned short smem[30336];   // 60672 B

    const int x = blockIdx.x;
    const int c = x & 15, bh = x >> 4;
    const int b = bh >> 4, h = bh & 15;
    const int tid = threadIdx.x;
    const int w = tid >> 6, lane = tid & 63;
    const int ml = lane & 15, quad = lane >> 4, kg8 = quad * 8;
    const size_t rowbase = (size_t)(b * LL + c * CHUNK);
    const size_t Sbase = (size_t)x * SROW;

    // ---- early prefetch of ST slice kq=0 ----
    const unsigned short* stp = STg + Sbase + (size_t)(quad >> 1) * 1280 + (quad & 1) * 8;
    bf16x8_t stf[2][5];
#pragma unroll
    for (int nt = 0; nt < 5; ++nt)
        stf[0][nt] = *(const bf16x8_t*)(stp + (nt * 16 + ml) * 16);

    // ---- load Q (padded + small) and K (padded) ----
    {
        const int row = tid >> 1, half = tid & 1;
        uint4 qv = *(const uint4*)(qkv_ro + (rowbase + row) * QKVLD + h * 16 + half * 8);
        *(uint4*)&smem[OFF_QP + row * 40 + half * 8] = qv;
        *(uint4*)&smem[OFF_QP + row * 40 + 16 + half * 8] = (uint4){0, 0, 0, 0};
        *(uint4*)&smem[OFF_QS + row * 16 + half * 8] = qv;
        uint4 kv = *(const uint4*)(qkv_ro + (rowbase + row) * QKVLD + 256 + h * 16 + half * 8);
        *(uint4*)&smem[OFF_KP + row * 40 + half * 8] = kv;
        *(uint4*)&smem[OFF_KP + row * 40 + 16 + half * 8] = (uint4){0, 0, 0, 0};
    }
    __syncthreads();

    // ---- phase 1: scores ----
    {
        bf16x8_t q0 = *(const bf16x8_t*)&smem[OFF_QP + (w * 32 + ml) * 40 + kg8];
        bf16x8_t q1 = *(const bf16x8_t*)&smem[OFF_QP + (w * 32 + 16 + ml) * 40 + kg8];
#pragma unroll
        for (int nt = 0; nt < 8; ++nt) {
            bf16x8_t kf = *(const bf16x8_t*)&smem[OFF_KP + (nt * 16 + ml) * 40 + kg8];
            f32x4_t a0 = __builtin_amdgcn_mfma_f32_16x16x32_bf16(q0, kf, (f32x4_t){0,0,0,0}, 0, 0, 0);
            f32x4_t a1 = __builtin_amdgcn_mfma_f32_16x16x32_bf16(q1, kf, (f32x4_t){0,0,0,0}, 0, 0, 0);
            const int j = nt * 16 + ml;
#pragma unroll
            for (int r = 0; r < 4; ++r) {
                int i0 = w * 32 + quad * 4 + r;
                float s0 = a0[r] * 0.25f;
                float v0 = (j <= i0) ? (1.f + s0 + 0.5f * s0 * s0) : 0.f;
                smem[OFF_A + i0 * 136 + j] = f2b(v0);
                int i1 = i0 + 16;
                float s1 = a1[r] * 0.25f;
                float v1 = (j <= i1) ? (1.f + s1 + 0.5f * s1 * s1) : 0.f;
                smem[OFF_A + i1 * 136 + j] = f2b(v1);
            }
        }
    }
    const int r0 = w * 32 + ml, r1 = r0 + 16;
    float qA[16], qB[16];
    {
        bf16x8_t t0 = *(const bf16x8_t*)&smem[OFF_QS + r0 * 16];
        bf16x8_t t1 = *(const bf16x8_t*)&smem[OFF_QS + r0 * 16 + 8];
        bf16x8_t t2 = *(const bf16x8_t*)&smem[OFF_QS + r1 * 16];
        bf16x8_t t3 = *(const bf16x8_t*)&smem[OFF_QS + r1 * 16 + 8];
#pragma unroll
        for (int i = 0; i < 8; ++i) {
            qA[i] = b2f((unsigned short)t0[i]); qA[8 + i] = b2f((unsigned short)t1[i]);
            qB[i] = b2f((unsigned short)t2[i]); qB[8 + i] = b2f((unsigned short)t3[i]);
        }
    }
    __syncthreads();

    // ---- load VT (overlays Qpad/Kpad) ----
    {
        const int row = tid >> 1, half = tid & 1;
#pragma unroll
        for (int cc = 0; cc < 4; ++cc) {
            uint4 vv = *(const uint4*)(qkv_ro + (rowbase + row) * QKVLD + 512 + h * 64 + half * 32 + cc * 8);
            const unsigned short* vp = (const unsigned short*)&vv;
#pragma unroll
            for (int i = 0; i < 8; ++i) smem[OFF_VT + (half * 32 + cc * 8 + i) * 136 + row] = vp[i];
        }
        if (half == 0) {
            smem[OFF_VT + 64 * 136 + row] = 0x3F80;
        } else {
#pragma unroll
            for (int e = 65; e < 80; ++e) smem[OFF_VT + e * 136 + row] = 0;
        }
    }
    __syncthreads();

    f32x4_t acc[2][5];
#pragma unroll
    for (int mt = 0; mt < 2; ++mt)
#pragma unroll
        for (int nt = 0; nt < 5; ++nt) acc[mt][nt] = (f32x4_t){0.f, 0.f, 0.f, 0.f};

    // ---- phase 2a: A @ V_ext ----
#pragma unroll
    for (int ks = 0; ks < 4; ++ks) {
        bf16x8_t af0 = *(const bf16x8_t*)&smem[OFF_A + (w * 32 + ml) * 136 + ks * 32 + kg8];
        bf16x8_t af1 = *(const bf16x8_t*)&smem[OFF_A + (w * 32 + 16 + ml) * 136 + ks * 32 + kg8];
#pragma unroll
        for (int nt = 0; nt < 5; ++nt) {
            bf16x8_t bv = *(const bf16x8_t*)&smem[OFF_VT + (nt * 16 + ml) * 136 + ks * 32 + kg8];
            acc[0][nt] = __builtin_amdgcn_mfma_f32_16x16x32_bf16(af0, bv, acc[0][nt], 0, 0, 0);
            acc[1][nt] = __builtin_amdgcn_mfma_f32_16x16x32_bf16(af1, bv, acc[1][nt], 0, 0, 0);
        }
    }

    // ---- phase 2b: Qf @ S_ext, barrier-free, double-buffered global reads ----
#pragma unroll
    for (int kq = 0; kq < 9; ++kq) {
        if (kq < 8) {
#pragma unroll
            for (int nt = 0; nt < 5; ++nt)
                stf[(kq + 1) & 1][nt] =
                    *(const bf16x8_t*)(stp + (size_t)(kq + 1) * 2560 + (nt * 16 + ml) * 16);
        }
        bf16x8_t qf[2];
#pragma unroll
        for (int mt = 0; mt < 2; ++mt) {
            const float* q = (mt == 0) ? qA : qB;
            const int qsrow = (mt == 0) ? r0 : r1;
            const int d0 = kq * 32 + kg8;
            unsigned short o[8];
            if (d0 >= 24 && d0 < 280) {
                const int e0 = d0 - 24;
                const float qa = b2f(smem[OFF_QS + qsrow * 16 + (e0 >> 4)]) * INV_R2RD;
                if ((e0 & 15) == 0) {
#pragma unroll
                    for (int j = 0; j < 8; ++j) o[j] = f2b(qa * q[j]);
                } else {
#pragma unroll
                    for (int j = 0; j < 8; ++j) o[j] = f2b(qa * q[8 + j]);
                }
            } else if (d0 == 0) {
                o[0] = 0x3F80;
#pragma unroll
                for (int j = 1; j < 8; ++j) o[j] = f2b(q[j - 1] * 0.5f);
            } else if (d0 == 8) {
#pragma unroll
                for (int j = 0; j < 8; ++j) o[j] = f2b(q[7 + j] * 0.5f);
            } else if (d0 == 16) {
                o[0] = f2b(q[15] * 0.5f);
#pragma unroll
                for (int j = 1; j < 8; ++j) o[j] = 0;
            } else {
#pragma unroll
                for (int j = 0; j < 8; ++j) o[j] = 0;
            }
            qf[mt] = *(const bf16x8_t*)o;
        }
#pragma unroll
        for (int nt = 0; nt < 5; ++nt) {
            acc[0][nt] = __builtin_amdgcn_mfma_f32_16x16x32_bf16(qf[0], stf[kq & 1][nt], acc[0][nt], 0, 0, 0);
            acc[1][nt] = __builtin_amdgcn_mfma_f32_16x16x32_bf16(qf[1], stf[kq & 1][nt], acc[1][nt], 0, 0, 0);
        }
    }

    // ---- epilogue: y = num / (den + eps), den = col 64 (nt=4, ml==0 lanes) ----
#pragma unroll
    for (int mt = 0; mt < 2; ++mt) {
        float den[4];
#pragma unroll
        for (int r = 0; r < 4; ++r) den[r] = __shfl(acc[mt][4][r], lane & 48);
#pragma unroll
        for (int r = 0; r < 4; ++r) {
            const size_t grow = rowbase + w * 32 + mt * 16 + quad * 4 + r;
            const float rc = 1.f / (den[r] + EPS);
#pragma unroll
            for (int nt = 0; nt < 4; ++nt)
                qkv_w[grow * QKVLD + 512 + h * 64 + nt * 16 + ml] = f2b(acc[mt][nt][r] * rc);
        }
    }
}

// ---------------------------------------------------------------------------
extern "C" void kernel_launch(void* const* d_in, const int* in_sizes, int n_in,
                              void* d_out, int out_size, void* d_ws, size_t ws_size,
                              hipStream_t stream)
{
    (void)in_sizes; (void)n_in; (void)out_size; (void)ws_size;
    const float* hs = (const float*)d_in[0];
    const float* Wq = (const float*)d_in[1];
    const float* Wk = (const float*)d_in[2];
    const float* Wv = (const float*)d_in[3];
    const float* Wo = (const float*)d_in[4];
    float* out = (float*)d_out;

    const int M = BB * LL;  // 8192
    char* ws = (char*)d_ws;
    unsigned short* STg   = (unsigned short*)ws;                           // 47,185,920 B
    size_t off = 47185920;
    unsigned short* qkv   = (unsigned short*)(ws + off); off += 25165824;  // 8192x1536
    unsigned short* Wqkv  = (unsigned short*)(ws + off); off += 3145728;   // 1536x1024
    unsigned short* Wo_bf = (unsigned short*)(ws + off); off += 2097152;   // total 77.6 MB

    cast_w<<<2560, 256, 0, stream>>>(Wq, Wk, Wv, Wo, Wqkv, Wo_bf);
    gemm_qkv<<<dim3(12, 64), 256, 0, stream>>>(hs, Wqkv, qkv, M, 1536, DM, DM, DM, QKVLD);
    state_kernel<<<1024, 256, 0, stream>>>(qkv, STg);
    scan_S<<<dim3(12, 64), 256, 0, stream>>>(STg);
    out_kernel<<<1024, 256, 0, stream>>>(qkv, STg, qkv);   // y in-place over v cols
    gemm_bf16<float><<<dim3(8, 64), 256, 0, stream>>>(qkv + 512, Wo_bf, out,
                                                      M, DM, DM, QKVLD, DM, DM);
}

// Round 6
// 218.488 us; speedup vs baseline: 1.0193x; 1.0193x over previous
//
#include <hip/hip_runtime.h>
#include <hip/hip_bf16.h>

#define BB 4
#define LL 2048
#define DM 1024
#define NH 16
#define FEAT 16
#define HD 64
#define CHUNK 128
#define NCHUNK 16
#define NEXT 80               // 64 v-cols + 1 ones-col + 15 pad
#define SROW 23040            // 18 dtiles x 80 e x 16 d = per-(bh,c) slab elems
#define EPS 1e-12f
#define INV_R2RD 0.17677669529663688f   // 1/(4*sqrt(2))
#define QKVLD 1536

typedef short bf16x8_t __attribute__((ext_vector_type(8)));
typedef float f32x4_t  __attribute__((ext_vector_type(4)));

__device__ __forceinline__ float b2f(unsigned short u) {
    union { unsigned int i; float f; } x; x.i = ((unsigned int)u) << 16; return x.f;
}
__device__ __forceinline__ unsigned short f2b(float f) {
    __hip_bfloat16 h = __float2bfloat16(f);
    return *reinterpret_cast<unsigned short*>(&h);
}

// ---------------------------------------------------------------------------
// Weight casts only (hs cast is fused into the qkv GEMM's A staging).
// ---------------------------------------------------------------------------
__global__ __launch_bounds__(256)
void cast_w(const float* __restrict__ wq, const float* __restrict__ wk,
            const float* __restrict__ wv, const float* __restrict__ wo,
            unsigned short* __restrict__ wqkv, unsigned short* __restrict__ wo_bf)
{
    const int i = (blockIdx.x * 256 + threadIdx.x) * 4;
    const float* s; unsigned short* d;
    if (i < 262144)       { s = wq + i;             d = wqkv + i; }
    else if (i < 524288)  { s = wk + (i - 262144);  d = wqkv + i; }
    else if (i < 1572864) { s = wv + (i - 524288);  d = wqkv + i; }
    else if (i < 2621440) { s = wo + (i - 1572864); d = wo_bf + (i - 1572864); }
    else return;
    float4 v = *(const float4*)s;
    ushort4 o; o.x = f2b(v.x); o.y = f2b(v.y); o.z = f2b(v.z); o.w = f2b(v.w);
    *(ushort4*)d = o;
}

// ---------------------------------------------------------------------------
// bf16 MFMA GEMM: C[M,N] = A[M,K] @ Bw[N,K]^T (fp32 acc).
// 128x128 tile, BK=32, 256 threads, m97 recipe + XOR bank swizzle
// (conflicts measured 0 in round 5).
// ---------------------------------------------------------------------------
template <typename OutT>
__global__ __launch_bounds__(256)
void gemm_bf16(const unsigned short* __restrict__ A, const unsigned short* __restrict__ Bw,
               OutT* __restrict__ C, int M, int N, int K, int lda, int ldb, int ldc)
{
    __shared__ unsigned short As[128 * 32];
    __shared__ unsigned short Bs[128 * 32];
    const int tid  = threadIdx.x;
    const int wave = tid >> 6, lane = tid & 63;
    const int m0 = blockIdx.y * 128, n0 = blockIdx.x * 128;
    const int wm = (wave >> 1) * 64, wn = (wave & 1) * 64;
    const int srow = tid >> 2;
    const int skc  = tid & 3;
    const int gkc  = skc ^ ((srow >> 1) & 3);   // swizzled global chunk
    const int ml = lane & 15, qq = lane >> 4;

    f32x4_t acc[4][4];
#pragma unroll
    for (int i = 0; i < 4; ++i)
#pragma unroll
        for (int j = 0; j < 4; ++j) acc[i][j] = (f32x4_t){0.f, 0.f, 0.f, 0.f};

    for (int k0 = 0; k0 < K; k0 += 32) {
#pragma unroll
        for (int p = 0; p < 2; ++p) {
            const int row = p * 64 + srow;
            const unsigned short* ga = A  + (size_t)(m0 + row) * lda + k0 + gkc * 8;
            const unsigned short* gb = Bw + (size_t)(n0 + row) * ldb + k0 + gkc * 8;
            unsigned short* la = As + (size_t)(p * 64 + wave * 16) * 32;
            unsigned short* lb = Bs + (size_t)(p * 64 + wave * 16) * 32;
            __builtin_amdgcn_global_load_lds((const __attribute__((address_space(1))) void*)ga,
                                             (__attribute__((address_space(3))) void*)la, 16, 0, 0);
            __builtin_amdgcn_global_load_lds((const __attribute__((address_space(1))) void*)gb,
                                             (__attribute__((address_space(3))) void*)lb, 16, 0, 0);
        }
        __syncthreads();
        bf16x8_t af[4], bfr[4];
#pragma unroll
        for (int i = 0; i < 4; ++i) {
            const int ra = wm + i * 16 + ml, rb = wn + i * 16 + ml;
            af[i]  = *(const bf16x8_t*)(As + ra * 32 + (qq ^ ((ra >> 1) & 3)) * 8);
            bfr[i] = *(const bf16x8_t*)(Bs + rb * 32 + (qq ^ ((rb >> 1) & 3)) * 8);
        }
#pragma unroll
        for (int i = 0; i < 4; ++i)
#pragma unroll
            for (int j = 0; j < 4; ++j)
                acc[i][j] = __builtin_amdgcn_mfma_f32_16x16x32_bf16(af[i], bfr[j], acc[i][j], 0, 0, 0);
        __syncthreads();
    }
#pragma unroll
    for (int i = 0; i < 4; ++i) {
        const int rbase = m0 + wm + i * 16 + qq * 4;
#pragma unroll
        for (int j = 0; j < 4; ++j) {
            const int col = n0 + wn + j * 16 + ml;
#pragma unroll
            for (int r = 0; r < 4; ++r) {
                const float v = acc[i][j][r];
                if constexpr (sizeof(OutT) == 2) {
                    ((unsigned short*)C)[(size_t)(rbase + r) * ldc + col] = f2b(v);
                } else {
                    ((float*)C)[(size_t)(rbase + r) * ldc + col] = v;
                }
            }
        }
    }
}

// ---------------------------------------------------------------------------
// qkv GEMM, fused fp32->bf16 cast on A, SOFTWARE-PIPELINED staging:
// A(k0) held in VGPRs is ds_written at iteration top; A(k0+32) loads are
// issued right after the first barrier so they overlap the 16 MFMAs
// (waitcnt lands before next iteration's ds_write). B via global_load_lds.
// ---------------------------------------------------------------------------
__global__ __launch_bounds__(256)
void gemm_qkv(const float* __restrict__ A, const unsigned short* __restrict__ Bw,
              unsigned short* __restrict__ C, int M, int N, int K, int lda, int ldb, int ldc)
{
    __shared__ unsigned short As[128 * 32];
    __shared__ unsigned short Bs[128 * 32];
    const int tid  = threadIdx.x;
    const int wave = tid >> 6, lane = tid & 63;
    const int m0 = blockIdx.y * 128, n0 = blockIdx.x * 128;
    const int wm = (wave >> 1) * 64, wn = (wave & 1) * 64;
    const int srow = tid >> 2;
    const int skc  = tid & 3;
    const int gkc  = skc ^ ((srow >> 1) & 3);
    const int ml = lane & 15, qq = lane >> 4;

    const float* ga0 = A + (size_t)(m0 + srow) * lda + gkc * 8;
    const float* ga1 = A + (size_t)(m0 + 64 + srow) * lda + gkc * 8;

    f32x4_t acc[4][4];
#pragma unroll
    for (int i = 0; i < 4; ++i)
#pragma unroll
        for (int j = 0; j < 4; ++j) acc[i][j] = (f32x4_t){0.f, 0.f, 0.f, 0.f};

    // prologue: A(0) into registers
    float4 ar[2][2];
    ar[0][0] = *(const float4*)ga0; ar[0][1] = *(const float4*)(ga0 + 4);
    ar[1][0] = *(const float4*)ga1; ar[1][1] = *(const float4*)(ga1 + 4);

    for (int k0 = 0; k0 < K; k0 += 32) {
        // stage A(k0) from regs (cvt + ds_write_b128), B async
#pragma unroll
        for (int p = 0; p < 2; ++p) {
            unsigned short pk[8];
            pk[0] = f2b(ar[p][0].x); pk[1] = f2b(ar[p][0].y);
            pk[2] = f2b(ar[p][0].z); pk[3] = f2b(ar[p][0].w);
            pk[4] = f2b(ar[p][1].x); pk[5] = f2b(ar[p][1].y);
            pk[6] = f2b(ar[p][1].z); pk[7] = f2b(ar[p][1].w);
            *(bf16x8_t*)(As + (size_t)(p * 64 + srow) * 32 + skc * 8) = *(const bf16x8_t*)pk;
            const unsigned short* gb = Bw + (size_t)(n0 + p * 64 + srow) * ldb + k0 + gkc * 8;
            unsigned short* lb = Bs + (size_t)(p * 64 + wave * 16) * 32;
            __builtin_amdgcn_global_load_lds((const __attribute__((address_space(1))) void*)gb,
                                             (__attribute__((address_space(3))) void*)lb, 16, 0, 0);
        }
        __syncthreads();
        // prefetch A(k0+32) — overlaps the MFMA block below
        if (k0 + 32 < K) {
            ar[0][0] = *(const float4*)(ga0 + k0 + 32);
            ar[0][1] = *(const float4*)(ga0 + k0 + 36);
            ar[1][0] = *(const float4*)(ga1 + k0 + 32);
            ar[1][1] = *(const float4*)(ga1 + k0 + 36);
        }
        bf16x8_t af[4], bfr[4];
#pragma unroll
        for (int i = 0; i < 4; ++i) {
            const int ra = wm + i * 16 + ml, rb = wn + i * 16 + ml;
            af[i]  = *(const bf16x8_t*)(As + ra * 32 + (qq ^ ((ra >> 1) & 3)) * 8);
            bfr[i] = *(const bf16x8_t*)(Bs + rb * 32 + (qq ^ ((rb >> 1) & 3)) * 8);
        }
#pragma unroll
        for (int i = 0; i < 4; ++i)
#pragma unroll
            for (int j = 0; j < 4; ++j)
                acc[i][j] = __builtin_amdgcn_mfma_f32_16x16x32_bf16(af[i], bfr[j], acc[i][j], 0, 0, 0);
        __syncthreads();
    }
#pragma unroll
    for (int i = 0; i < 4; ++i) {
        const int rbase = m0 + wm + i * 16 + qq * 4;
#pragma unroll
        for (int j = 0; j < 4; ++j) {
            const int col = n0 + wn + j * 16 + ml;
#pragma unroll
            for (int r = 0; r < 4; ++r)
                C[(size_t)(rbase + r) * ldc + col] = f2b(acc[i][j][r]);
        }
    }
}

// ---------------------------------------------------------------------------
// state_kernel: per (bh,c) computes S_c = Kf^T @ V_ext (MFMA), stored in the
// TILED layout: slab[dtile 0..17][e 0..79][dlocal 0..15], d = dtile*16+dlocal.
// Feature order d: [1][q/2 x16][0 x7][qxq/(4sqrt2) x256][0 x8]; e=64 -> z.
// ---------------------------------------------------------------------------
__global__ __launch_bounds__(256)
void state_kernel(const unsigned short* __restrict__ qkv, unsigned short* __restrict__ STg)
{
    __shared__ unsigned short KT[16 * 136];   // K transposed [f][j], padded
    __shared__ unsigned short VT[80 * 136];   // V_ext transposed [e][j], padded

    const int x = blockIdx.x;
    const int c = x & 15, bh = x >> 4;
    const int b = bh >> 4, h = bh & 15;
    const int tid = threadIdx.x;
    const int wave = tid >> 6, lane = tid & 63;
    const int ml = lane & 15, kg8 = (lane >> 4) * 8;
    const size_t rowbase = (size_t)(b * LL + c * CHUNK);
    const size_t Sbase = (size_t)x * SROW;

    {
        const int row = tid >> 1, half = tid & 1;
        uint4 kv = *(const uint4*)(qkv + (rowbase + row) * QKVLD + 256 + h * 16 + half * 8);
        const unsigned short* kp = (const unsigned short*)&kv;
#pragma unroll
        for (int i = 0; i < 8; ++i) KT[(half * 8 + i) * 136 + row] = kp[i];
#pragma unroll
        for (int cc = 0; cc < 4; ++cc) {
            uint4 vv = *(const uint4*)(qkv + (rowbase + row) * QKVLD + 512 + h * 64 + half * 32 + cc * 8);
            const unsigned short* vp = (const unsigned short*)&vv;
#pragma unroll
            for (int i = 0; i < 8; ++i) VT[(half * 32 + cc * 8 + i) * 136 + row] = vp[i];
        }
        if (half == 0) {
            VT[64 * 136 + row] = 0x3F80;   // ones column
        } else {
#pragma unroll
            for (int e = 65; e < 80; ++e) VT[e * 136 + row] = 0;
        }
    }
    __syncthreads();

    bf16x8_t bfr[5][4];
#pragma unroll
    for (int nt = 0; nt < 5; ++nt)
#pragma unroll
        for (int ks = 0; ks < 4; ++ks)
            bfr[nt][ks] = *(const bf16x8_t*)&VT[(nt * 16 + ml) * 136 + ks * 32 + kg8];

    for (int mt = wave; mt < 18; mt += 4) {
        const int d = mt * 16 + ml;
        bf16x8_t af[4];
#pragma unroll
        for (int ks = 0; ks < 4; ++ks) {
            const int jb = ks * 32 + kg8;
            unsigned short o[8];
            if (d >= 24 && d < 280) {
                const int e = d - 24, a = e >> 4, bq = e & 15;
                bf16x8_t ka = *(const bf16x8_t*)&KT[a  * 136 + jb];
                bf16x8_t kb = *(const bf16x8_t*)&KT[bq * 136 + jb];
#pragma unroll
                for (int j = 0; j < 8; ++j)
                    o[j] = f2b(b2f((unsigned short)ka[j]) * b2f((unsigned short)kb[j]) * INV_R2RD);
            } else if (d == 0) {
#pragma unroll
                for (int j = 0; j < 8; ++j) o[j] = 0x3F80;
            } else if (d <= 16) {
                bf16x8_t kx = *(const bf16x8_t*)&KT[(d - 1) * 136 + jb];
#pragma unroll
                for (int j = 0; j < 8; ++j) o[j] = f2b(b2f((unsigned short)kx[j]) * 0.5f);
            } else {
#pragma unroll
                for (int j = 0; j < 8; ++j) o[j] = 0;
            }
            af[ks] = *(const bf16x8_t*)o;
        }
        f32x4_t acc[5];
#pragma unroll
        for (int nt = 0; nt < 5; ++nt) acc[nt] = (f32x4_t){0.f, 0.f, 0.f, 0.f};
#pragma unroll
        for (int nt = 0; nt < 5; ++nt)
#pragma unroll
            for (int ks = 0; ks < 4; ++ks)
                acc[nt] = __builtin_amdgcn_mfma_f32_16x16x32_bf16(af[ks], bfr[nt][ks], acc[nt], 0, 0, 0);
#pragma unroll
        for (int nt = 0; nt < 5; ++nt) {
            ushort4 pk;
            pk.x = f2b(acc[nt][0]); pk.y = f2b(acc[nt][1]);
            pk.z = f2b(acc[nt][2]); pk.w = f2b(acc[nt][3]);
            *(ushort4*)(STg + Sbase + (size_t)mt * 1280 + (nt * 16 + ml) * 16 + (lane >> 4) * 4) = pk;
        }
    }
}

// ---------------------------------------------------------------------------
// scan: exclusive prefix over the 16 chunks, elementwise, uint4 per thread.
// ---------------------------------------------------------------------------
__global__ __launch_bounds__(256)
void scan_S(unsigned short* __restrict__ STg) {
    const int bh  = blockIdx.y;
    const int idx = blockIdx.x * 256 + threadIdx.x;   // uint4 index, 0..2879
    if (idx >= SROW / 8) return;
    const size_t base = (size_t)bh * NCHUNK * SROW + (size_t)idx * 8;
    float acc[8] = {};
    for (int c = 0; c < NCHUNK; ++c) {
        unsigned short* p = STg + base + (size_t)c * SROW;
        uint4 v = *(const uint4*)p;
        const unsigned short* vp = (const unsigned short*)&v;
        uint4 o;
        unsigned short* op = (unsigned short*)&o;
#pragma unroll
        for (int i = 0; i < 8; ++i) { op[i] = f2b(acc[i]); acc[i] += b2f(vp[i]); }
        *(uint4*)p = o;
    }
}

// ---------------------------------------------------------------------------
// out_kernel: per (bh,c), 256 threads / 4 waves (unchanged from round 4).
// ---------------------------------------------------------------------------
#define OFF_VT 0
#define OFF_QP 0
#define OFF_KP 5120
#define OFF_A  10880
#define OFF_QS 28288

__global__ __launch_bounds__(256)
void out_kernel(const unsigned short* __restrict__ qkv_ro, const unsigned short* __restrict__ STg,
                unsigned short* __restrict__ qkv_w)
{
    __shared__ unsigned short smem[30336];   // 60672 B

    const int x = blockIdx.x;
    const int c = x & 15, bh = x >> 4;
    const int b = bh >> 4, h = bh & 15;
    const int tid = threadIdx.x;
    const int w = tid >> 6, lane = tid & 63;
    const int ml = lane & 15, quad = lane >> 4, kg8 = quad * 8;
    const size_t rowbase = (size_t)(b * LL + c * CHUNK);
    const size_t Sbase = (size_t)x * SROW;

    // ---- early prefetch of ST slice kq=0 ----
    const unsigned short* stp = STg + Sbase + (size_t)(quad >> 1) * 1280 + (quad & 1) * 8;
    bf16x8_t stf[2][5];
#pragma unroll
    for (int nt = 0; nt < 5; ++nt)
        stf[0][nt] = *(const bf16x8_t*)(stp + (nt * 16 + ml) * 16);

    // ---- load Q (padded + small) and K (padded) ----
    {
        const int row = tid >> 1, half = tid & 1;
        uint4 qv = *(const uint4*)(qkv_ro + (rowbase + row) * QKVLD + h * 16 + half * 8);
        *(uint4*)&smem[OFF_QP + row * 40 + half * 8] = qv;
        *(uint4*)&smem[OFF_QP + row * 40 + 16 + half * 8] = (uint4){0, 0, 0, 0};
        *(uint4*)&smem[OFF_QS + row * 16 + half * 8] = qv;
        uint4 kv = *(const uint4*)(qkv_ro + (rowbase + row) * QKVLD + 256 + h * 16 + half * 8);
        *(uint4*)&smem[OFF_KP + row * 40 + half * 8] = kv;
        *(uint4*)&smem[OFF_KP + row * 40 + 16 + half * 8] = (uint4){0, 0, 0, 0};
    }
    __syncthreads();

    // ---- phase 1: scores ----
    {
        bf16x8_t q0 = *(const bf16x8_t*)&smem[OFF_QP + (w * 32 + ml) * 40 + kg8];
        bf16x8_t q1 = *(const bf16x8_t*)&smem[OFF_QP + (w * 32 + 16 + ml) * 40 + kg8];
#pragma unroll
        for (int nt = 0; nt < 8; ++nt) {
            bf16x8_t kf = *(const bf16x8_t*)&smem[OFF_KP + (nt * 16 + ml) * 40 + kg8];
            f32x4_t a0 = __builtin_amdgcn_mfma_f32_16x16x32_bf16(q0, kf, (f32x4_t){0,0,0,0}, 0, 0, 0);
            f32x4_t a1 = __builtin_amdgcn_mfma_f32_16x16x32_bf16(q1, kf, (f32x4_t){0,0,0,0}, 0, 0, 0);
            const int j = nt * 16 + ml;
#pragma unroll
            for (int r = 0; r < 4; ++r) {
                int i0 = w * 32 + quad * 4 + r;
                float s0 = a0[r] * 0.25f;
                float v0 = (j <= i0) ? (1.f + s0 + 0.5f * s0 * s0) : 0.f;
                smem[OFF_A + i0 * 136 + j] = f2b(v0);
                int i1 = i0 + 16;
                float s1 = a1[r] * 0.25f;
                float v1 = (j <= i1) ? (1.f + s1 + 0.5f * s1 * s1) : 0.f;
                smem[OFF_A + i1 * 136 + j] = f2b(v1);
            }
        }
    }
    const int r0 = w * 32 + ml, r1 = r0 + 16;
    float qA[16], qB[16];
    {
        bf16x8_t t0 = *(const bf16x8_t*)&smem[OFF_QS + r0 * 16];
        bf16x8_t t1 = *(const bf16x8_t*)&smem[OFF_QS + r0 * 16 + 8];
        bf16x8_t t2 = *(const bf16x8_t*)&smem[OFF_QS + r1 * 16];
        bf16x8_t t3 = *(const bf16x8_t*)&smem[OFF_QS + r1 * 16 + 8];
#pragma unroll
        for (int i = 0; i < 8; ++i) {
            qA[i] = b2f((unsigned short)t0[i]); qA[8 + i] = b2f((unsigned short)t1[i]);
            qB[i] = b2f((unsigned short)t2[i]); qB[8 + i] = b2f((unsigned short)t3[i]);
        }
    }
    __syncthreads();

    // ---- load VT (overlays Qpad/Kpad) ----
    {
        const int row = tid >> 1, half = tid & 1;
#pragma unroll
        for (int cc = 0; cc < 4; ++cc) {
            uint4 vv = *(const uint4*)(qkv_ro + (rowbase + row) * QKVLD + 512 + h * 64 + half * 32 + cc * 8);
            const unsigned short* vp = (const unsigned short*)&vv;
#pragma unroll
            for (int i = 0; i < 8; ++i) smem[OFF_VT + (half * 32 + cc * 8 + i) * 136 + row] = vp[i];
        }
        if (half == 0) {
            smem[OFF_VT + 64 * 136 + row] = 0x3F80;
        } else {
#pragma unroll
            for (int e = 65; e < 80; ++e) smem[OFF_VT + e * 136 + row] = 0;
        }
    }
    __syncthreads();

    f32x4_t acc[2][5];
#pragma unroll
    for (int mt = 0; mt < 2; ++mt)
#pragma unroll
        for (int nt = 0; nt < 5; ++nt) acc[mt][nt] = (f32x4_t){0.f, 0.f, 0.f, 0.f};

    // ---- phase 2a: A @ V_ext ----
#pragma unroll
    for (int ks = 0; ks < 4; ++ks) {
        bf16x8_t af0 = *(const bf16x8_t*)&smem[OFF_A + (w * 32 + ml) * 136 + ks * 32 + kg8];
        bf16x8_t af1 = *(const bf16x8_t*)&smem[OFF_A + (w * 32 + 16 + ml) * 136 + ks * 32 + kg8];
#pragma unroll
        for (int nt = 0; nt < 5; ++nt) {
            bf16x8_t bv = *(const bf16x8_t*)&smem[OFF_VT + (nt * 16 + ml) * 136 + ks * 32 + kg8];
            acc[0][nt] = __builtin_amdgcn_mfma_f32_16x16x32_bf16(af0, bv, acc[0][nt], 0, 0, 0);
            acc[1][nt] = __builtin_amdgcn_mfma_f32_16x16x32_bf16(af1, bv, acc[1][nt], 0, 0, 0);
        }
    }

    // ---- phase 2b: Qf @ S_ext, barrier-free, double-buffered global reads ----
#pragma unroll
    for (int kq = 0; kq < 9; ++kq) {
        if (kq < 8) {
#pragma unroll
            for (int nt = 0; nt < 5; ++nt)
                stf[(kq + 1) & 1][nt] =
                    *(const bf16x8_t*)(stp + (size_t)(kq + 1) * 2560 + (nt * 16 + ml) * 16);
        }
        bf16x8_t qf[2];
#pragma unroll
        for (int mt = 0; mt < 2; ++mt) {
            const float* q = (mt == 0) ? qA : qB;
            const int qsrow = (mt == 0) ? r0 : r1;
            const int d0 = kq * 32 + kg8;
            unsigned short o[8];
            if (d0 >= 24 && d0 < 280) {
                const int e0 = d0 - 24;
                const float qa = b2f(smem[OFF_QS + qsrow * 16 + (e0 >> 4)]) * INV_R2RD;
                if ((e0 & 15) == 0) {
#pragma unroll
                    for (int j = 0; j < 8; ++j) o[j] = f2b(qa * q[j]);
                } else {
#pragma unroll
                    for (int j = 0; j < 8; ++j) o[j] = f2b(qa * q[8 + j]);
                }
            } else if (d0 == 0) {
                o[0] = 0x3F80;
#pragma unroll
                for (int j = 1; j < 8; ++j) o[j] = f2b(q[j - 1] * 0.5f);
            } else if (d0 == 8) {
#pragma unroll
                for (int j = 0; j < 8; ++j) o[j] = f2b(q[7 + j] * 0.5f);
            } else if (d0 == 16) {
                o[0] = f2b(q[15] * 0.5f);
#pragma unroll
                for (int j = 1; j < 8; ++j) o[j] = 0;
            } else {
#pragma unroll
                for (int j = 0; j < 8; ++j) o[j] = 0;
            }
            qf[mt] = *(const bf16x8_t*)o;
        }
#pragma unroll
        for (int nt = 0; nt < 5; ++nt) {
            acc[0][nt] = __builtin_amdgcn_mfma_f32_16x16x32_bf16(qf[0], stf[kq & 1][nt], acc[0][nt], 0, 0, 0);
            acc[1][nt] = __builtin_amdgcn_mfma_f32_16x16x32_bf16(qf[1], stf[kq & 1][nt], acc[1][nt], 0, 0, 0);
        }
    }

    // ---- epilogue: y = num / (den + eps), den = col 64 (nt=4, ml==0 lanes) ----
#pragma unroll
    for (int mt = 0; mt < 2; ++mt) {
        float den[4];
#pragma unroll
        for (int r = 0; r < 4; ++r) den[r] = __shfl(acc[mt][4][r], lane & 48);
#pragma unroll
        for (int r = 0; r < 4; ++r) {
            const size_t grow = rowbase + w * 32 + mt * 16 + quad * 4 + r;
            const float rc = 1.f / (den[r] + EPS);
#pragma unroll
            for (int nt = 0; nt < 4; ++nt)
                qkv_w[grow * QKVLD + 512 + h * 64 + nt * 16 + ml] = f2b(acc[mt][nt][r] * rc);
        }
    }
}

// ---------------------------------------------------------------------------
extern "C" void kernel_launch(void* const* d_in, const int* in_sizes, int n_in,
                              void* d_out, int out_size, void* d_ws, size_t ws_size,
                              hipStream_t stream)
{
    (void)in_sizes; (void)n_in; (void)out_size; (void)ws_size;
    const float* hs = (const float*)d_in[0];
    const float* Wq = (const float*)d_in[1];
    const float* Wk = (const float*)d_in[2];
    const float* Wv = (const float*)d_in[3];
    const float* Wo = (const float*)d_in[4];
    float* out = (float*)d_out;

    const int M = BB * LL;  // 8192
    char* ws = (char*)d_ws;
    unsigned short* STg   = (unsigned short*)ws;                           // 47,185,920 B
    size_t off = 47185920;
    unsigned short* qkv   = (unsigned short*)(ws + off); off += 25165824;  // 8192x1536
    unsigned short* Wqkv  = (unsigned short*)(ws + off); off += 3145728;   // 1536x1024
    unsigned short* Wo_bf = (unsigned short*)(ws + off); off += 2097152;   // total 77.6 MB

    cast_w<<<2560, 256, 0, stream>>>(Wq, Wk, Wv, Wo, Wqkv, Wo_bf);
    gemm_qkv<<<dim3(12, 64), 256, 0, stream>>>(hs, Wqkv, qkv, M, 1536, DM, DM, DM, QKVLD);
    state_kernel<<<1024, 256, 0, stream>>>(qkv, STg);
    scan_S<<<dim3(12, 64), 256, 0, stream>>>(STg);
    out_kernel<<<1024, 256, 0, stream>>>(qkv, STg, qkv);   // y in-place over v cols
    gemm_bf16<float><<<dim3(8, 64), 256, 0, stream>>>(qkv + 512, Wo_bf, out,
                                                      M, DM, DM, QKVLD, DM, DM);
}